// Round 3
// baseline (61.354 us; speedup 1.0000x reference)
//
#include <hip/hip_runtime.h>
#include <hip/hip_cooperative_groups.h>

namespace cg = cooperative_groups;

#define B_ 512
#define I_ 256
#define O_ 256
#define K_ 8
#define BT 2
#define NB (B_ / BT)   // 256 blocks; must equal thread count of guard-reduce (256)

static constexpr float NORM_F    = 0.7978845608028654f;   // 1/(0.5*sqrt(2*pi))
static constexpr float LOG2E_F   = 1.4426950408889634f;
static constexpr float NEG2LOG2E = -2.8853900817779268f;  // exp(-2 d^2) = exp2(NEG2LOG2E * d^2)

__device__ __forceinline__ void wave_reduce5(float& cpmin, float& cpmax,
                                             float& xm, float& cfm, float& wm) {
    for (int off = 32; off; off >>= 1) {
        cpmin = fminf(cpmin, __shfl_xor(cpmin, off));
        cpmax = fmaxf(cpmax, __shfl_xor(cpmax, off));
        xm    = fmaxf(xm,    __shfl_xor(xm, off));
        cfm   = fmaxf(cfm,   __shfl_xor(cfm, off));
        wm    = fmaxf(wm,    __shfl_xor(wm, off));
    }
}

__device__ __forceinline__ void guard_partial(int tid, int nthr,
                                              const float* __restrict__ x,
                                              const float* __restrict__ cp,
                                              const float* __restrict__ cf,
                                              const float* __restrict__ w,
                                              float& cpmin, float& cpmax,
                                              float& xm, float& cfm, float& wm) {
    cpmin = 1e30f; cpmax = -1e30f; xm = 0.0f; cfm = 0.0f; wm = 0.0f;
    const float4* cp4 = reinterpret_cast<const float4*>(cp);
    const float4* cf4 = reinterpret_cast<const float4*>(cf);
    const float4* x4  = reinterpret_cast<const float4*>(x);
    const float4* w4  = reinterpret_cast<const float4*>(w);
    for (int i = tid; i < I_ * O_ * K_ / 4; i += nthr) {
        float4 v = cp4[i];
        cpmin = fminf(cpmin, fminf(fminf(v.x, v.y), fminf(v.z, v.w)));
        cpmax = fmaxf(cpmax, fmaxf(fmaxf(v.x, v.y), fmaxf(v.z, v.w)));
    }
    for (int i = tid; i < I_ * O_ * K_ / 4; i += nthr) {
        float4 v = cf4[i];
        cfm = fmaxf(cfm, fmaxf(fmaxf(fabsf(v.x), fabsf(v.y)), fmaxf(fabsf(v.z), fabsf(v.w))));
    }
    for (int i = tid; i < B_ * I_ / 4; i += nthr) {
        float4 v = x4[i];
        xm = fmaxf(xm, fmaxf(fmaxf(fabsf(v.x), fabsf(v.y)), fmaxf(fabsf(v.z), fabsf(v.w))));
    }
    for (int i = tid; i < I_ * O_ / 4; i += nthr) {
        float4 v = w4[i];
        wm = fmaxf(wm, fmaxf(fmaxf(fabsf(v.x), fabsf(v.y)), fmaxf(fabsf(v.z), fabsf(v.w))));
    }
}

// ---------- single cooperative kernel: scan -> grid.sync -> compute ----------
__global__ __launch_bounds__(256) void kan_coop(const float* __restrict__ x,
                                                const float* __restrict__ cp,
                                                const float* __restrict__ cf,
                                                const float* __restrict__ w,
                                                float* __restrict__ g,
                                                float* __restrict__ out) {
    const int o   = threadIdx.x;
    const int bid = blockIdx.x;
    const int b0  = bid * BT;

    __shared__ float red[4][5];
    __shared__ float si[BT][I_];
    __shared__ float sx[BT][I_];

    // stage x + silu(x) rows for this block (independent of scan; overlaps)
#pragma unroll
    for (int b = 0; b < BT; ++b) {
        float v = x[(b0 + b) * I_ + o];
        float e = __builtin_amdgcn_exp2f(-v * LOG2E_F);
        sx[b][o] = v;
        si[b][o] = v * __builtin_amdgcn_rcpf(1.0f + e);
    }

    // phase A: guard partial scan (vec4, grid-strided)
    float cpmin, cpmax, xm, cfm, wm;
    guard_partial(bid * 256 + o, NB * 256, x, cp, cf, w, cpmin, cpmax, xm, cfm, wm);
    wave_reduce5(cpmin, cpmax, xm, cfm, wm);
    const int wv = o >> 6, ln = o & 63;
    if (ln == 0) { red[wv][0] = cpmin; red[wv][1] = cpmax; red[wv][2] = xm; red[wv][3] = cfm; red[wv][4] = wm; }
    __syncthreads();
    if (o == 0) {
        float a = fminf(fminf(red[0][0], red[1][0]), fminf(red[2][0], red[3][0]));
        float bq = fmaxf(fmaxf(red[0][1], red[1][1]), fmaxf(red[2][1], red[3][1]));
        float c = fmaxf(fmaxf(red[0][2], red[1][2]), fmaxf(red[2][2], red[3][2]));
        float d = fmaxf(fmaxf(red[0][3], red[1][3]), fmaxf(red[2][3], red[3][3]));
        float e = fmaxf(fmaxf(red[0][4], red[1][4]), fmaxf(red[2][4], red[3][4]));
        float* p = g + bid * 8;
        p[0] = a; p[1] = bq; p[2] = c; p[3] = d; p[4] = e;
    }
    __threadfence();
    cg::this_grid().sync();

    // phase B: reduce the NB partials (one slot per thread), decide path
    {
        const float* p = g + o * 8;
        cpmin = p[0]; cpmax = p[1]; xm = p[2]; cfm = p[3]; wm = p[4];
    }
    wave_reduce5(cpmin, cpmax, xm, cfm, wm);
    if (ln == 0) { red[wv][0] = cpmin; red[wv][1] = cpmax; red[wv][2] = xm; red[wv][3] = cfm; red[wv][4] = wm; }
    __syncthreads();
    cpmin = fminf(fminf(red[0][0], red[1][0]), fminf(red[2][0], red[3][0]));
    cpmax = fmaxf(fmaxf(red[0][1], red[1][1]), fmaxf(red[2][1], red[3][1]));
    xm    = fmaxf(fmaxf(red[0][2], red[1][2]), fmaxf(red[2][2], red[3][2]));
    cfm   = fmaxf(fmaxf(red[0][3], red[1][3]), fmaxf(red[2][3], red[3][3]));
    wm    = fmaxf(fmaxf(red[0][4], red[1][4]), fmaxf(red[2][4], red[3][4]));
    float dist  = fmaxf(0.0f, fmaxf(cpmin - xm, -cpmax - xm));
    float bmax  = __builtin_amdgcn_exp2f(NEG2LOG2E * dist * dist);
    float bound = NORM_F * bmax * (float)K_ * (float)I_ * wm * cfm;
    const bool skip = (bound < 1e-7f);   // grid-uniform (same reduction everywhere)

    float acc[BT];
#pragma unroll
    for (int b = 0; b < BT; ++b) acc[b] = 0.0f;

    if (skip) {
        // fast path: out[b,o] = sum_i w[i,o] * silu(x[b,i])
#pragma unroll 16
        for (int i = 0; i < I_; ++i) {
            const float wv_ = w[i * O_ + o];
#pragma unroll
            for (int b = 0; b < BT; ++b) acc[b] = fmaf(wv_, si[b][i], acc[b]);
        }
    } else {
        // full path: Gaussian spline term included (correct for any input)
        for (int i = 0; i < I_; ++i) {
            const int io = i * O_ + o;
            const float4 c0 = reinterpret_cast<const float4*>(cp + io * K_)[0];
            const float4 c1 = reinterpret_cast<const float4*>(cp + io * K_)[1];
            const float4 f0 = reinterpret_cast<const float4*>(cf + io * K_)[0];
            const float4 f1 = reinterpret_cast<const float4*>(cf + io * K_)[1];
            const float wv_ = w[io];
            const float wn  = wv_ * NORM_F;
#pragma unroll
            for (int b = 0; b < BT; ++b) {
                const float xb = sx[b][i];
                float s = 0.0f, d, e;
                d = xb - c0.x; e = __builtin_amdgcn_exp2f(d * d * NEG2LOG2E); s = fmaf(e, f0.x, s);
                d = xb - c0.y; e = __builtin_amdgcn_exp2f(d * d * NEG2LOG2E); s = fmaf(e, f0.y, s);
                d = xb - c0.z; e = __builtin_amdgcn_exp2f(d * d * NEG2LOG2E); s = fmaf(e, f0.z, s);
                d = xb - c0.w; e = __builtin_amdgcn_exp2f(d * d * NEG2LOG2E); s = fmaf(e, f0.w, s);
                d = xb - c1.x; e = __builtin_amdgcn_exp2f(d * d * NEG2LOG2E); s = fmaf(e, f1.x, s);
                d = xb - c1.y; e = __builtin_amdgcn_exp2f(d * d * NEG2LOG2E); s = fmaf(e, f1.y, s);
                d = xb - c1.z; e = __builtin_amdgcn_exp2f(d * d * NEG2LOG2E); s = fmaf(e, f1.z, s);
                d = xb - c1.w; e = __builtin_amdgcn_exp2f(d * d * NEG2LOG2E); s = fmaf(e, f1.w, s);
                acc[b] = fmaf(wv_, si[b][i], acc[b]);
                acc[b] = fmaf(wn, s, acc[b]);
            }
        }
    }

#pragma unroll
    for (int b = 0; b < BT; ++b)
        out[(b0 + b) * O_ + o] = acc[b];
}

// ---------- fallback two-kernel path (proven in R2) ----------
__global__ __launch_bounds__(256) void guard_scan(const float* __restrict__ x,
                                                  const float* __restrict__ cp,
                                                  const float* __restrict__ cf,
                                                  const float* __restrict__ w,
                                                  float* __restrict__ g) {
    float cpmin, cpmax, xm, cfm, wm;
    guard_partial(blockIdx.x * 256 + threadIdx.x, NB * 256, x, cp, cf, w,
                  cpmin, cpmax, xm, cfm, wm);
    wave_reduce5(cpmin, cpmax, xm, cfm, wm);
    __shared__ float s[4][5];
    const int wv = threadIdx.x >> 6, ln = threadIdx.x & 63;
    if (ln == 0) { s[wv][0] = cpmin; s[wv][1] = cpmax; s[wv][2] = xm; s[wv][3] = cfm; s[wv][4] = wm; }
    __syncthreads();
    if (threadIdx.x == 0) {
        for (int q = 1; q < 4; ++q) {
            s[0][0] = fminf(s[0][0], s[q][0]);
            s[0][1] = fmaxf(s[0][1], s[q][1]);
            s[0][2] = fmaxf(s[0][2], s[q][2]);
            s[0][3] = fmaxf(s[0][3], s[q][3]);
            s[0][4] = fmaxf(s[0][4], s[q][4]);
        }
        float* p = g + blockIdx.x * 8;
        p[0] = s[0][0]; p[1] = s[0][1]; p[2] = s[0][2]; p[3] = s[0][3]; p[4] = s[0][4];
    }
}

__global__ __launch_bounds__(256) void kan_fused(const float* __restrict__ x,
                                                 const float* __restrict__ cp,
                                                 const float* __restrict__ cf,
                                                 const float* __restrict__ w,
                                                 const float* __restrict__ g,  // may be null
                                                 float* __restrict__ out) {
    const int o  = threadIdx.x;
    const int b0 = blockIdx.x * BT;

    __shared__ float red[4][5];
    __shared__ float si[BT][I_];
    __shared__ float sx[BT][I_];

    bool skip = false;
    if (g) {
        const float* p = g + threadIdx.x * 8;
        float cpmin = p[0], cpmax = p[1], xm = p[2], cfm = p[3], wm = p[4];
        wave_reduce5(cpmin, cpmax, xm, cfm, wm);
        const int wv = threadIdx.x >> 6, ln = threadIdx.x & 63;
        if (ln == 0) { red[wv][0] = cpmin; red[wv][1] = cpmax; red[wv][2] = xm; red[wv][3] = cfm; red[wv][4] = wm; }
        __syncthreads();
        cpmin = fminf(fminf(red[0][0], red[1][0]), fminf(red[2][0], red[3][0]));
        cpmax = fmaxf(fmaxf(red[0][1], red[1][1]), fmaxf(red[2][1], red[3][1]));
        xm    = fmaxf(fmaxf(red[0][2], red[1][2]), fmaxf(red[2][2], red[3][2]));
        cfm   = fmaxf(fmaxf(red[0][3], red[1][3]), fmaxf(red[2][3], red[3][3]));
        wm    = fmaxf(fmaxf(red[0][4], red[1][4]), fmaxf(red[2][4], red[3][4]));
        float dist  = fmaxf(0.0f, fmaxf(cpmin - xm, -cpmax - xm));
        float bmax  = __builtin_amdgcn_exp2f(NEG2LOG2E * dist * dist);
        float bound = NORM_F * bmax * (float)K_ * (float)I_ * wm * cfm;
        skip = (bound < 1e-7f);
    }

#pragma unroll
    for (int b = 0; b < BT; ++b) {
        float v = x[(b0 + b) * I_ + o];
        float e = __builtin_amdgcn_exp2f(-v * LOG2E_F);
        sx[b][o] = v;
        si[b][o] = v * __builtin_amdgcn_rcpf(1.0f + e);
    }
    __syncthreads();

    float acc[BT];
#pragma unroll
    for (int b = 0; b < BT; ++b) acc[b] = 0.0f;

    if (skip) {
#pragma unroll 16
        for (int i = 0; i < I_; ++i) {
            const float wv_ = w[i * O_ + o];
#pragma unroll
            for (int b = 0; b < BT; ++b) acc[b] = fmaf(wv_, si[b][i], acc[b]);
        }
    } else {
        for (int i = 0; i < I_; ++i) {
            const int io = i * O_ + o;
            const float4 c0 = reinterpret_cast<const float4*>(cp + io * K_)[0];
            const float4 c1 = reinterpret_cast<const float4*>(cp + io * K_)[1];
            const float4 f0 = reinterpret_cast<const float4*>(cf + io * K_)[0];
            const float4 f1 = reinterpret_cast<const float4*>(cf + io * K_)[1];
            const float wv_ = w[io];
            const float wn  = wv_ * NORM_F;
#pragma unroll
            for (int b = 0; b < BT; ++b) {
                const float xb = sx[b][i];
                float s = 0.0f, d, e;
                d = xb - c0.x; e = __builtin_amdgcn_exp2f(d * d * NEG2LOG2E); s = fmaf(e, f0.x, s);
                d = xb - c0.y; e = __builtin_amdgcn_exp2f(d * d * NEG2LOG2E); s = fmaf(e, f0.y, s);
                d = xb - c0.z; e = __builtin_amdgcn_exp2f(d * d * NEG2LOG2E); s = fmaf(e, f0.z, s);
                d = xb - c0.w; e = __builtin_amdgcn_exp2f(d * d * NEG2LOG2E); s = fmaf(e, f0.w, s);
                d = xb - c1.x; e = __builtin_amdgcn_exp2f(d * d * NEG2LOG2E); s = fmaf(e, f1.x, s);
                d = xb - c1.y; e = __builtin_amdgcn_exp2f(d * d * NEG2LOG2E); s = fmaf(e, f1.y, s);
                d = xb - c1.z; e = __builtin_amdgcn_exp2f(d * d * NEG2LOG2E); s = fmaf(e, f1.z, s);
                d = xb - c1.w; e = __builtin_amdgcn_exp2f(d * d * NEG2LOG2E); s = fmaf(e, f1.w, s);
                acc[b] = fmaf(wv_, si[b][i], acc[b]);
                acc[b] = fmaf(wn, s, acc[b]);
            }
        }
    }

#pragma unroll
    for (int b = 0; b < BT; ++b)
        out[(b0 + b) * O_ + o] = acc[b];
}

extern "C" void kernel_launch(void* const* d_in, const int* in_sizes, int n_in,
                              void* d_out, int out_size, void* d_ws, size_t ws_size,
                              hipStream_t stream) {
    const float* x  = (const float*)d_in[0];
    const float* cp = (const float*)d_in[1];
    const float* cf = (const float*)d_in[2];
    const float* w  = (const float*)d_in[3];
    float* out = (float*)d_out;

    const size_t guard_bytes = (size_t)NB * 8 * sizeof(float);

    if (ws_size >= guard_bytes) {
        float* g = (float*)d_ws;
        void* args[] = { (void*)&x, (void*)&cp, (void*)&cf, (void*)&w, (void*)&g, (void*)&out };
        hipError_t err = hipLaunchCooperativeKernel((const void*)kan_coop,
                                                    dim3(NB), dim3(256), args, 0, stream);
        if (err == hipSuccess) return;
        // fall through to two-kernel path if cooperative launch is unavailable
        guard_scan<<<NB, 256, 0, stream>>>(x, cp, cf, w, g);
        kan_fused<<<B_ / BT, 256, 0, stream>>>(x, cp, cf, w, g, out);
    } else {
        kan_fused<<<B_ / BT, 256, 0, stream>>>(x, cp, cf, w, nullptr, out);
    }
}

// Round 4
// 16.378 us; speedup vs baseline: 3.7462x; 3.7462x over previous
//
#include <hip/hip_runtime.h>

#define B_ 512
#define I_ 256
#define O_ 256
#define K_ 8
#define NB 256        // guard partial slots == guard grid size

static constexpr float NORM_F    = 0.7978845608028654f;   // 1/(0.5*sqrt(2*pi))
static constexpr float LOG2E_F   = 1.4426950408889634f;
static constexpr float NEG2LOG2E = -2.8853900817779268f;  // exp(-2 d^2) = exp2(NEG2LOG2E * d^2)

__device__ __forceinline__ void wave_reduce5(float& cpmin, float& cpmax,
                                             float& xm, float& cfm, float& wm) {
    for (int off = 32; off; off >>= 1) {
        cpmin = fminf(cpmin, __shfl_xor(cpmin, off));
        cpmax = fmaxf(cpmax, __shfl_xor(cpmax, off));
        xm    = fmaxf(xm,    __shfl_xor(xm, off));
        cfm   = fmaxf(cfm,   __shfl_xor(cfm, off));
        wm    = fmaxf(wm,    __shfl_xor(wm, off));
    }
}

// k1: float4 scan of all inputs -> per-block {cp_min, cp_max, max|x|, max|cf|, max|w|}.
__global__ __launch_bounds__(256) void guard_scan(const float* __restrict__ x,
                                                  const float* __restrict__ cp,
                                                  const float* __restrict__ cf,
                                                  const float* __restrict__ w,
                                                  float* __restrict__ g) {
    const int tid  = blockIdx.x * 256 + threadIdx.x;
    const int nthr = NB * 256;
    float cpmin = 1e30f, cpmax = -1e30f, xm = 0.0f, cfm = 0.0f, wm = 0.0f;
    const float4* cp4 = reinterpret_cast<const float4*>(cp);
    const float4* cf4 = reinterpret_cast<const float4*>(cf);
    const float4* x4  = reinterpret_cast<const float4*>(x);
    const float4* w4  = reinterpret_cast<const float4*>(w);
#pragma unroll
    for (int i = tid; i < I_ * O_ * K_ / 4; i += nthr) {
        float4 v = cp4[i];
        cpmin = fminf(cpmin, fminf(fminf(v.x, v.y), fminf(v.z, v.w)));
        cpmax = fmaxf(cpmax, fmaxf(fmaxf(v.x, v.y), fmaxf(v.z, v.w)));
    }
#pragma unroll
    for (int i = tid; i < I_ * O_ * K_ / 4; i += nthr) {
        float4 v = cf4[i];
        cfm = fmaxf(cfm, fmaxf(fmaxf(fabsf(v.x), fabsf(v.y)), fmaxf(fabsf(v.z), fabsf(v.w))));
    }
#pragma unroll
    for (int i = tid; i < B_ * I_ / 4; i += nthr) {
        float4 v = x4[i];
        xm = fmaxf(xm, fmaxf(fmaxf(fabsf(v.x), fabsf(v.y)), fmaxf(fabsf(v.z), fabsf(v.w))));
    }
#pragma unroll
    for (int i = tid; i < I_ * O_ / 4; i += nthr) {
        float4 v = w4[i];
        wm = fmaxf(wm, fmaxf(fmaxf(fabsf(v.x), fabsf(v.y)), fmaxf(fabsf(v.z), fabsf(v.w))));
    }
    wave_reduce5(cpmin, cpmax, xm, cfm, wm);
    __shared__ float s[4][5];
    const int wv = threadIdx.x >> 6, ln = threadIdx.x & 63;
    if (ln == 0) { s[wv][0] = cpmin; s[wv][1] = cpmax; s[wv][2] = xm; s[wv][3] = cfm; s[wv][4] = wm; }
    __syncthreads();
    if (threadIdx.x == 0) {
        for (int q = 1; q < 4; ++q) {
            s[0][0] = fminf(s[0][0], s[q][0]);
            s[0][1] = fmaxf(s[0][1], s[q][1]);
            s[0][2] = fmaxf(s[0][2], s[q][2]);
            s[0][3] = fmaxf(s[0][3], s[q][3]);
            s[0][4] = fmaxf(s[0][4], s[q][4]);
        }
        float* p = g + blockIdx.x * 8;
        p[0] = s[0][0]; p[1] = s[0][1]; p[2] = s[0][2]; p[3] = s[0][3]; p[4] = s[0][4];
    }
}

// k2: 512 threads = 8 waves; thread = (h, o) with h = b-half. 256 blocks (2 b's each).
// Reduces guard partials redundantly per block (cheap), then fast GEMM path or
// full Gaussian path (correct for arbitrary inputs).
__global__ __launch_bounds__(512) void kan_fused(const float* __restrict__ x,
                                                 const float* __restrict__ cp,
                                                 const float* __restrict__ cf,
                                                 const float* __restrict__ w,
                                                 const float* __restrict__ g,  // may be null
                                                 float* __restrict__ out) {
    const int t = threadIdx.x;
    const int o = t & (O_ - 1);
    const int h = t >> 8;            // 0 or 1
    const int b = blockIdx.x * 2 + h;

    __shared__ float red[8][5];
    __shared__ float si[2][I_];
    __shared__ float sx[2][I_];

    // stage x + silu(x) for this block's two rows (independent of guard)
    {
        float v = x[b * I_ + o];
        float e = __builtin_amdgcn_exp2f(-v * LOG2E_F);
        sx[h][o] = v;
        si[h][o] = v * __builtin_amdgcn_rcpf(1.0f + e);
    }

    // reduce guard partials: 256 slots, each read twice (harmless for min/max)
    bool skip = false;
    if (g) {
        const float* p = g + (t & (NB - 1)) * 8;
        float cpmin = p[0], cpmax = p[1], xm = p[2], cfm = p[3], wm = p[4];
        wave_reduce5(cpmin, cpmax, xm, cfm, wm);
        const int wv = t >> 6, ln = t & 63;
        if (ln == 0) { red[wv][0] = cpmin; red[wv][1] = cpmax; red[wv][2] = xm; red[wv][3] = cfm; red[wv][4] = wm; }
        __syncthreads();
        cpmin = red[0][0]; cpmax = red[0][1]; xm = red[0][2]; cfm = red[0][3]; wm = red[0][4];
#pragma unroll
        for (int q = 1; q < 8; ++q) {
            cpmin = fminf(cpmin, red[q][0]);
            cpmax = fmaxf(cpmax, red[q][1]);
            xm    = fmaxf(xm,    red[q][2]);
            cfm   = fmaxf(cfm,   red[q][3]);
            wm    = fmaxf(wm,    red[q][4]);
        }
        float dist  = fmaxf(0.0f, fmaxf(cpmin - xm, -cpmax - xm));
        float bmax  = __builtin_amdgcn_exp2f(NEG2LOG2E * dist * dist);
        float bound = NORM_F * bmax * (float)K_ * (float)I_ * wm * cfm;
        skip = (bound < 1e-7f);      // grid-uniform
    } else {
        __syncthreads();             // match the sync for LDS staging below
    }
    __syncthreads();                 // si/sx visible to all

    float acc = 0.0f;

    if (skip) {
        // fast path: out[b,o] = sum_i w[i,o] * silu(x[b,i]); w loads coalesced, L2-hit
#pragma unroll 32
        for (int i = 0; i < I_; ++i)
            acc = fmaf(w[i * O_ + o], si[h][i], acc);
    } else {
        // full path with Gaussian spline term
        for (int i = 0; i < I_; ++i) {
            const int io = i * O_ + o;
            const float4 c0 = reinterpret_cast<const float4*>(cp + io * K_)[0];
            const float4 c1 = reinterpret_cast<const float4*>(cp + io * K_)[1];
            const float4 f0 = reinterpret_cast<const float4*>(cf + io * K_)[0];
            const float4 f1 = reinterpret_cast<const float4*>(cf + io * K_)[1];
            const float wv_ = w[io];
            const float wn  = wv_ * NORM_F;
            const float xb  = sx[h][i];
            float s = 0.0f, d, e;
            d = xb - c0.x; e = __builtin_amdgcn_exp2f(d * d * NEG2LOG2E); s = fmaf(e, f0.x, s);
            d = xb - c0.y; e = __builtin_amdgcn_exp2f(d * d * NEG2LOG2E); s = fmaf(e, f0.y, s);
            d = xb - c0.z; e = __builtin_amdgcn_exp2f(d * d * NEG2LOG2E); s = fmaf(e, f0.z, s);
            d = xb - c0.w; e = __builtin_amdgcn_exp2f(d * d * NEG2LOG2E); s = fmaf(e, f0.w, s);
            d = xb - c1.x; e = __builtin_amdgcn_exp2f(d * d * NEG2LOG2E); s = fmaf(e, f1.x, s);
            d = xb - c1.y; e = __builtin_amdgcn_exp2f(d * d * NEG2LOG2E); s = fmaf(e, f1.y, s);
            d = xb - c1.z; e = __builtin_amdgcn_exp2f(d * d * NEG2LOG2E); s = fmaf(e, f1.z, s);
            d = xb - c1.w; e = __builtin_amdgcn_exp2f(d * d * NEG2LOG2E); s = fmaf(e, f1.w, s);
            acc = fmaf(wv_, si[h][i], acc);
            acc = fmaf(wn, s, acc);
        }
    }

    out[b * O_ + o] = acc;
}

extern "C" void kernel_launch(void* const* d_in, const int* in_sizes, int n_in,
                              void* d_out, int out_size, void* d_ws, size_t ws_size,
                              hipStream_t stream) {
    const float* x  = (const float*)d_in[0];
    const float* cp = (const float*)d_in[1];
    const float* cf = (const float*)d_in[2];
    const float* w  = (const float*)d_in[3];
    float* out = (float*)d_out;

    const size_t guard_bytes = (size_t)NB * 8 * sizeof(float);

    float* g = nullptr;
    if (ws_size >= guard_bytes) {
        g = (float*)d_ws;
        guard_scan<<<NB, 256, 0, stream>>>(x, cp, cf, w, g);
    }
    kan_fused<<<B_ / 2, 512, 0, stream>>>(x, cp, cf, w, g, out);
}

// Round 5
// 16.129 us; speedup vs baseline: 3.8040x; 1.0154x over previous
//
#include <hip/hip_runtime.h>

#define B_ 512
#define I_ 256
#define O_ 256
#define K_ 8

#define OSL 8                    // o's per block
#define BTL 32                   // b's per tile
#define NTILE 2                  // tiles per block -> 64 b per block
#define NOS (O_ / OSL)           // 32 o-slices
#define NBT (B_ / (BTL * NTILE)) // 8 b-groups; grid = 32*8 = 256 blocks

static constexpr float NORM_F    = 0.7978845608028654f;   // 1/(0.5*sqrt(2*pi))
static constexpr float LOG2E_F   = 1.4426950408889634f;
static constexpr float NEG2LOG2E = -2.8853900817779268f;  // exp(-2 d^2) = exp2(NEG2LOG2E * d^2)

// Single-dispatch KAN layer. Each block owns an 8-o slice x 64-b range, so the
// spline-negligibility guard is block-local (scans only this block's cp/cf/w
// slice) -- no second kernel, no grid sync, no workspace. Falls back to the
// exact Gaussian-spline path per tile if the bound is not provably negligible.
__global__ __launch_bounds__(512) void kan_one(const float* __restrict__ x,
                                               const float* __restrict__ cp,
                                               const float* __restrict__ cf,
                                               const float* __restrict__ w,
                                               float* __restrict__ out) {
    const int t   = threadIdx.x;
    const int os  = blockIdx.x & (NOS - 1);
    const int bt  = blockIdx.x >> 5;            // / NOS
    const int o0  = os * OSL;
    const int bg0 = bt * (BTL * NTILE);

    __shared__ float si[BTL][I_];   // silu(x), swizzled: si[b][i ^ ((b&3)<<3)]
    __shared__ float wl[I_][OSL];   // w[:, o-slice]
    __shared__ float red[8][4];
    __shared__ float redx[8];

    const int wave = t >> 6, lane = t & 63;

    // ---- phase A: w-slice -> LDS, and guard scan of cp/cf/w slice ----
    float cpmin = 1e30f, cpmax = -1e30f, cfm = 0.0f, wm = 0.0f;
    {
        const float4* w4 = reinterpret_cast<const float4*>(w);
        const int i = t >> 1, q = t & 1;
        float4 v = w4[i * (O_ / 4) + os * 2 + q];
        wl[i][q * 4 + 0] = v.x; wl[i][q * 4 + 1] = v.y;
        wl[i][q * 4 + 2] = v.z; wl[i][q * 4 + 3] = v.w;
        wm = fmaxf(fmaxf(fabsf(v.x), fabsf(v.y)), fmaxf(fabsf(v.z), fabsf(v.w)));

        const float4* cp4 = reinterpret_cast<const float4*>(cp);
        const float4* cf4 = reinterpret_cast<const float4*>(cf);
        const int ROW4 = O_ * K_ / 4;   // 512 float4 per i-row
#pragma unroll
        for (int r = 0; r < 8; ++r) {
            const int ind = r * 512 + t;
            const int i2 = ind >> 4, q2 = ind & 15;
            float4 a = cp4[i2 * ROW4 + os * 16 + q2];
            cpmin = fminf(cpmin, fminf(fminf(a.x, a.y), fminf(a.z, a.w)));
            cpmax = fmaxf(cpmax, fmaxf(fmaxf(a.x, a.y), fmaxf(a.z, a.w)));
            float4 c = cf4[i2 * ROW4 + os * 16 + q2];
            cfm = fmaxf(cfm, fmaxf(fmaxf(fabsf(c.x), fabsf(c.y)),
                                   fmaxf(fabsf(c.z), fabsf(c.w))));
        }
    }
    for (int off = 32; off; off >>= 1) {
        cpmin = fminf(cpmin, __shfl_xor(cpmin, off));
        cpmax = fmaxf(cpmax, __shfl_xor(cpmax, off));
        cfm   = fmaxf(cfm,   __shfl_xor(cfm, off));
        wm    = fmaxf(wm,    __shfl_xor(wm, off));
    }
    if (lane == 0) { red[wave][0] = cpmin; red[wave][1] = cpmax; red[wave][2] = cfm; red[wave][3] = wm; }
    __syncthreads();
    cpmin = red[0][0]; cpmax = red[0][1]; cfm = red[0][2]; wm = red[0][3];
#pragma unroll
    for (int q = 1; q < 8; ++q) {
        cpmin = fminf(cpmin, red[q][0]);
        cpmax = fmaxf(cpmax, red[q][1]);
        cfm   = fmaxf(cfm,   red[q][2]);
        wm    = fmaxf(wm,    red[q][3]);
    }

    // ---- phase B: per b-tile: stage silu -> decide -> accumulate ----
    const int o_ = t & 7, h = (t >> 3) & 1, b_ = t >> 4;   // b_ in 0..31

    for (int tile = 0; tile < NTILE; ++tile) {
        const int tb0 = bg0 + tile * BTL;
        if (tile) __syncthreads();   // previous tile's si reads complete

        // stage silu(x[tile]) into swizzled LDS; track tile max|x|
        float xm_t = 0.0f;
#pragma unroll
        for (int r = 0; r < 16; ++r) {
            const int ind = r * 512 + t;
            const int b = ind >> 8, i = ind & 255;
            float v = x[(tb0 + b) * I_ + i];
            xm_t = fmaxf(xm_t, fabsf(v));
            float e = __builtin_amdgcn_exp2f(-v * LOG2E_F);
            si[b][i ^ ((b & 3) << 3)] = v * __builtin_amdgcn_rcpf(1.0f + e);
        }
        for (int off = 32; off; off >>= 1) xm_t = fmaxf(xm_t, __shfl_xor(xm_t, off));
        if (lane == 0) redx[wave] = xm_t;
        __syncthreads();   // si staged + redx visible
        float xm = redx[0];
#pragma unroll
        for (int q = 1; q < 8; ++q) xm = fmaxf(xm, redx[q]);

        const float dist  = fmaxf(0.0f, fmaxf(cpmin - xm, -cpmax - xm));
        const float bmax  = __builtin_amdgcn_exp2f(NEG2LOG2E * dist * dist);
        const float bound = NORM_F * bmax * (float)K_ * (float)I_ * wm * cfm;
        const bool  skip  = (bound < 1e-7f);   // block-uniform

        float acc = 0.0f;
        if (skip) {
            // fast path: acc = sum_{i in half} w[i,o] * silu(x[b,i])
            const int swz = (b_ & 3) << 3;
#pragma unroll 8
            for (int i0 = h * 128; i0 < h * 128 + 128; i0 += 4) {
                const float4 s4 = *reinterpret_cast<const float4*>(&si[b_][i0 ^ swz]);
                acc = fmaf(wl[i0 + 0][o_], s4.x, acc);
                acc = fmaf(wl[i0 + 1][o_], s4.y, acc);
                acc = fmaf(wl[i0 + 2][o_], s4.z, acc);
                acc = fmaf(wl[i0 + 3][o_], s4.w, acc);
            }
        } else {
            // exact path: include the Gaussian spline term (rare; correctness)
            const int swz = (b_ & 3) << 3;
            for (int i = h * 128; i < h * 128 + 128; ++i) {
                const float xv = x[(tb0 + b_) * I_ + i];
                const float sv = si[b_][i ^ swz];
                const int io = i * O_ + o0 + o_;
                const float4 c0 = reinterpret_cast<const float4*>(cp + io * K_)[0];
                const float4 c1 = reinterpret_cast<const float4*>(cp + io * K_)[1];
                const float4 f0 = reinterpret_cast<const float4*>(cf + io * K_)[0];
                const float4 f1 = reinterpret_cast<const float4*>(cf + io * K_)[1];
                float s = 0.0f, d, e;
                d = xv - c0.x; e = __builtin_amdgcn_exp2f(d * d * NEG2LOG2E); s = fmaf(e, f0.x, s);
                d = xv - c0.y; e = __builtin_amdgcn_exp2f(d * d * NEG2LOG2E); s = fmaf(e, f0.y, s);
                d = xv - c0.z; e = __builtin_amdgcn_exp2f(d * d * NEG2LOG2E); s = fmaf(e, f0.z, s);
                d = xv - c0.w; e = __builtin_amdgcn_exp2f(d * d * NEG2LOG2E); s = fmaf(e, f0.w, s);
                d = xv - c1.x; e = __builtin_amdgcn_exp2f(d * d * NEG2LOG2E); s = fmaf(e, f1.x, s);
                d = xv - c1.y; e = __builtin_amdgcn_exp2f(d * d * NEG2LOG2E); s = fmaf(e, f1.y, s);
                d = xv - c1.z; e = __builtin_amdgcn_exp2f(d * d * NEG2LOG2E); s = fmaf(e, f1.z, s);
                d = xv - c1.w; e = __builtin_amdgcn_exp2f(d * d * NEG2LOG2E); s = fmaf(e, f1.w, s);
                acc = fmaf(wl[i][o_], sv + NORM_F * s, acc);
            }
        }

        acc += __shfl_xor(acc, 8);   // combine the two i-halves (h-bit = lane bit 3)
        if (h == 0)
            out[(tb0 + b_) * O_ + o0 + o_] = acc;
    }
}

extern "C" void kernel_launch(void* const* d_in, const int* in_sizes, int n_in,
                              void* d_out, int out_size, void* d_ws, size_t ws_size,
                              hipStream_t stream) {
    const float* x  = (const float*)d_in[0];
    const float* cp = (const float*)d_in[1];
    const float* cf = (const float*)d_in[2];
    const float* w  = (const float*)d_in[3];
    float* out = (float*)d_out;

    kan_one<<<NOS * NBT, 512, 0, stream>>>(x, cp, cf, w, out);
}